// Round 10
// baseline (548.658 us; speedup 1.0000x reference)
//
#include <hip/hip_runtime.h>

#define NVOX 300000
#define K27 27
#define VPB 128           // voxels per block (4 waves x 32)
#define TILES 2           // 16-row MFMA tiles per wave
#define NBLK 2344         // = ceil(NVOX/VPB), divisible by 8
#define CPX  (NBLK/8)     // chunks per XCD
#define NBLK0 1176        // conv0 grid: 8*147 (padded over 1172)
#define CPX0 (NBLK0/8)

typedef __attribute__((ext_vector_type(8))) __bf16 bf16x8;
typedef __attribute__((ext_vector_type(8))) unsigned short ushort8;
typedef __attribute__((ext_vector_type(4))) float f32x4;

__device__ inline unsigned short f2bf(float x){
  unsigned int u = __float_as_uint(x);
  unsigned int r = (u + 0x7FFFu + ((u >> 16) & 1u)) >> 16;   // RNE
  return (unsigned short)r;
}

// ---- pack conv weights ----
__global__ void pack_w_kernel(const float* __restrict__ bw, const float* __restrict__ w0,
                              unsigned short* __restrict__ pw, unsigned short* __restrict__ pw0){
  int t = blockIdx.x*256 + threadIdx.x;
  if (t < 4*K27*2*64){
    int l  = t & 63;
    int h  = (t >> 6) & 1;
    int k  = (t >> 7) % K27;
    int cv = t / (128*K27);
    int g = l >> 4, r16 = l & 15;
    ushort8 o;
    #pragma unroll
    for (int i = 0; i < 8; ++i){
      int c  = g*8 + i;
      int oc = h*16 + r16;
      o[i] = f2bf(bw[(((cv*K27 + k)*32) + c)*32 + oc]);
    }
    *reinterpret_cast<ushort8*>(pw + t*8) = o;
    return;
  }
  int u = t - 4*K27*2*64;
  if (u >= 4*2*64) return;
  int l  = u & 63;
  int h  = (u >> 6) & 1;
  int kb = u >> 7;
  int g = l >> 4, r16 = l & 15;
  int col = h*16 + r16;
  ushort8 o;
  #pragma unroll
  for (int i = 0; i < 8; ++i){
    int k   = kb*32 + g*8 + i;
    int tap = k >> 2, ch = k & 3;
    float v = (tap < K27 && ch < 3) ? w0[(tap*3 + ch)*32 + col] : 0.f;
    o[i] = f2bf(v);
  }
  *reinterpret_cast<ushort8*>(pw0 + u*8) = o;
}

// ---- pack head weights ----
__global__ void pack_hw_kernel(const float* __restrict__ w_cls, const float* __restrict__ b_cls,
                               const float* __restrict__ w_fe,  const float* __restrict__ b_fe,
                               const float* __restrict__ w_le,
                               const float* __restrict__ w_fr,  const float* __restrict__ b_fr,
                               unsigned short* __restrict__ pwh, float* __restrict__ bcat){
  int t = blockIdx.x*512 + threadIdx.x;
  if (t < 96){
    float v = 0.f;
    if (t < 32)      v = b_fe[t];
    else if (t < 64) v = b_fr[t-32];
    else if (t < 84) v = b_cls[t-64];
    bcat[t] = v;
  }
  if (t >= 8*64) return;
  int l = t & 63, f = t >> 6;
  int g = l >> 4, r16 = l & 15;
  ushort8 o;
  #pragma unroll
  for (int i = 0; i < 8; ++i){
    int k = g*8 + i;
    float v;
    if (f < 6){
      int col = f*16 + r16;
      if (col < 32)      v = w_fe[k*32 + col];
      else if (col < 64) v = w_fr[k*32 + (col-32)];
      else { int c = col - 64; v = (c < 20) ? w_cls[k*20 + c] : 0.f; }
    } else {
      int col = (f-6)*16 + r16;
      v = w_le[k*32 + col];
    }
    o[i] = f2bf(v);
  }
  *reinterpret_cast<ushort8*>(pwh + t*8) = o;
}

// ---- pre-pad features: [N,3] f32 -> [N+1][4] f32 (w=0, row N = 0 sentinel) ----
__global__ void prepad_kernel(const float* __restrict__ feats, f32x4* __restrict__ fpad){
  int row = blockIdx.x*256 + threadIdx.x;
  if (row > NVOX) return;
  f32x4 v = {0.f, 0.f, 0.f, 0.f};
  if (row < NVOX){
    v.x = feats[row*3+0]; v.y = feats[row*3+1]; v.z = feats[row*3+2];
  }
  fpad[row] = v;
}

// ---- conv0 via MFMA: XCD-chunked swizzle; nt on streaming traffic ----
__global__ void __launch_bounds__(256) conv0_mfma_kernel(
    const f32x4* __restrict__ fpad, const int* __restrict__ nbr,
    const unsigned short* __restrict__ pw0, float* __restrict__ trunk,
    float* __restrict__ stats){
  int bid   = blockIdx.x;
  int chunk = (bid & 7)*CPX0 + (bid >> 3);
  int base  = chunk*256;
  if (base >= NVOX) return;

  __shared__ int   snbr[256*K27];
  __shared__ float sstat[64];
  int tid = threadIdx.x;
  for (int i = tid; i < 256*K27; i += 256){
    int v = base + i / K27;
    snbr[i] = (v < NVOX) ? __builtin_nontemporal_load(&nbr[(size_t)base*K27 + i]) : NVOX;
  }
  if (tid < 64) sstat[tid] = 0.f;
  __syncthreads();

  int l = tid & 63, w = tid >> 6;
  int g = l >> 4, r16 = l & 15;
  const int vb = w*64;

  bf16x8 B[4][2];
  #pragma unroll
  for (int kb = 0; kb < 4; ++kb)
    #pragma unroll
    for (int h = 0; h < 2; ++h)
      B[kb][h] = *reinterpret_cast<const bf16x8*>(pw0 + (kb*2 + h)*512 + l*8);

  f32x4 acc[4][2];
  #pragma unroll
  for (int t = 0; t < 4; ++t)
    #pragma unroll
    for (int h = 0; h < 2; ++h)
      acc[t][h] = (f32x4){0.f,0.f,0.f,0.f};

  #pragma unroll
  for (int t = 0; t < 4; ++t){
    int row = (vb + t*16 + r16)*K27;
    #pragma unroll
    for (int kb = 0; kb < 4; ++kb){
      int tap0 = kb*8 + g*2;
      int tap1 = tap0 + 1;
      int i0 = (tap0 < K27) ? tap0 : 0;
      int i1 = (tap1 < K27) ? tap1 : 0;
      int j0 = snbr[row + i0]; if (tap0 >= K27) j0 = NVOX;
      int j1 = snbr[row + i1]; if (tap1 >= K27) j1 = NVOX;
      f32x4 v0 = fpad[j0];
      f32x4 v1 = fpad[j1];
      ushort8 au;
      au[0] = f2bf(v0.x); au[1] = f2bf(v0.y); au[2] = f2bf(v0.z); au[3] = 0;
      au[4] = f2bf(v1.x); au[5] = f2bf(v1.y); au[6] = f2bf(v1.z); au[7] = 0;
      bf16x8 a = __builtin_bit_cast(bf16x8, au);
      acc[t][0] = __builtin_amdgcn_mfma_f32_16x16x32_bf16(a, B[kb][0], acc[t][0], 0, 0, 0);
      acc[t][1] = __builtin_amdgcn_mfma_f32_16x16x32_bf16(a, B[kb][1], acc[t][1], 0, 0, 0);
    }
  }

  float s0[2] = {0.f, 0.f}, s1[2] = {0.f, 0.f};
  #pragma unroll
  for (int t = 0; t < 4; ++t){
    #pragma unroll
    for (int r = 0; r < 4; ++r){
      int row = base + vb + t*16 + g*4 + r;
      if (row < NVOX){
        #pragma unroll
        for (int h = 0; h < 2; ++h){
          float v = acc[t][h][r];
          __builtin_nontemporal_store(v, trunk + (size_t)row*32 + h*16 + r16);
          s0[h] += v; s1[h] += v*v;
        }
      }
    }
  }
  #pragma unroll
  for (int h = 0; h < 2; ++h){
    s0[h] += __shfl_xor(s0[h], 16);
    s0[h] += __shfl_xor(s0[h], 32);
    s1[h] += __shfl_xor(s1[h], 16);
    s1[h] += __shfl_xor(s1[h], 32);
  }
  if (l < 16){
    atomicAdd(&sstat[r16],      s0[0]);
    atomicAdd(&sstat[32 + r16], s1[0]);
    atomicAdd(&sstat[16 + r16], s0[1]);
    atomicAdd(&sstat[48 + r16], s1[1]);
  }
  __syncthreads();
  if (tid < 64) atomicAdd(&stats[(blockIdx.x & 63)*64 + tid], sstat[tid]);
}

// ---- activation with inline BN finalize; nt streaming ----
__global__ void __launch_bounds__(256) act_kernel(
    const float* __restrict__ trunk, const float* __restrict__ stats,
    const float* __restrict__ g, const float* __restrict__ b,
    unsigned short* __restrict__ act){
  __shared__ float sbnp[64];
  int tid = threadIdx.x;
  if (tid < 32){
    float s = 0.f, q = 0.f;
    #pragma unroll
    for (int i = 0; i < 64; ++i){ s += stats[i*64 + tid]; q += stats[i*64 + 32 + tid]; }
    float inv = 1.0f / (float)NVOX;
    float mu  = s * inv;
    float var = q * inv - mu*mu;
    float sc  = g[tid] * rsqrtf(var + 1e-4f);
    sbnp[tid]      = sc;
    sbnp[32 + tid] = b[tid] - mu*sc;
  }
  __syncthreads();

  int t = blockIdx.x*256 + tid;
  if (t >= (NVOX+1)*4) return;
  int row = t >> 2, part = t & 3;
  ushort8 o;
  if (row < NVOX){
    const f32x4* p = reinterpret_cast<const f32x4*>(trunk + (size_t)row*32 + part*8);
    f32x4 v0 = __builtin_nontemporal_load(p);
    f32x4 v1 = __builtin_nontemporal_load(p + 1);
    float vv[8] = {v0.x, v0.y, v0.z, v0.w, v1.x, v1.y, v1.z, v1.w};
    #pragma unroll
    for (int i = 0; i < 8; ++i){
      float v = vv[i]*sbnp[part*8 + i] + sbnp[32 + part*8 + i];
      v = fmaxf(v, 0.f);
      o[i] = f2bf(v);
    }
  } else {
    #pragma unroll
    for (int i = 0; i < 8; ++i) o[i] = 0;
  }
  __builtin_nontemporal_store(o, reinterpret_cast<ushort8*>(act + (size_t)row*32 + part*8));
}

// ---- MFMA conv 32->32; XCD-chunked swizzle so act gathers are L2-resident; nt streaming ----
template<bool RES>
__global__ void __launch_bounds__(256) conv_mfma_kernel(
    const unsigned short* __restrict__ act, const int* __restrict__ nbr,
    const unsigned short* __restrict__ pw, float* __restrict__ trunk,
    float* __restrict__ stats){
  int bid   = blockIdx.x;
  int chunk = (bid & 7)*CPX + (bid >> 3);
  const int base = chunk*VPB;

  __shared__ int   snbr[VPB*K27];
  __shared__ float sstat[64];
  int tid = threadIdx.x;
  for (int i = tid; i < VPB*K27; i += 256){
    int v = base + i / K27;
    snbr[i] = (v < NVOX) ? __builtin_nontemporal_load(&nbr[(size_t)base*K27 + i]) : NVOX;
  }
  if (tid < 64) sstat[tid] = 0.f;
  __syncthreads();

  int l = tid & 63, w = tid >> 6;
  int g = l >> 4, r16 = l & 15;
  const int vb = w*(TILES*16);

  int rb[TILES];
  #pragma unroll
  for (int t = 0; t < TILES; ++t) rb[t] = (vb + t*16 + r16)*K27;

  f32x4 acc[TILES][2];
  #pragma unroll
  for (int t = 0; t < TILES; ++t)
    #pragma unroll
    for (int h = 0; h < 2; ++h)
      acc[t][h] = (f32x4){0.f,0.f,0.f,0.f};

  #pragma unroll
  for (int k = 0; k < K27; ++k){
    bf16x8 b0 = *reinterpret_cast<const bf16x8*>(pw + (k*2    )*512 + l*8);
    bf16x8 b1 = *reinterpret_cast<const bf16x8*>(pw + (k*2 + 1)*512 + l*8);
    bf16x8 a[TILES];
    #pragma unroll
    for (int t = 0; t < TILES; ++t){
      int j = snbr[rb[t] + k];
      a[t] = *reinterpret_cast<const bf16x8*>(act + (size_t)j*32 + g*8);
    }
    #pragma unroll
    for (int t = 0; t < TILES; ++t){
      acc[t][0] = __builtin_amdgcn_mfma_f32_16x16x32_bf16(a[t], b0, acc[t][0], 0, 0, 0);
      acc[t][1] = __builtin_amdgcn_mfma_f32_16x16x32_bf16(a[t], b1, acc[t][1], 0, 0, 0);
    }
  }

  float s0[2] = {0.f, 0.f}, s1[2] = {0.f, 0.f};
  #pragma unroll
  for (int t = 0; t < TILES; ++t){
    #pragma unroll
    for (int r = 0; r < 4; ++r){
      int row = base + vb + t*16 + g*4 + r;
      if (row < NVOX){
        #pragma unroll
        for (int h = 0; h < 2; ++h){
          float v = acc[t][h][r];
          float* p = trunk + (size_t)row*32 + h*16 + r16;
          if (RES) v += __builtin_nontemporal_load(p);
          __builtin_nontemporal_store(v, p);
          s0[h] += v; s1[h] += v*v;
        }
      }
    }
  }
  #pragma unroll
  for (int h = 0; h < 2; ++h){
    s0[h] += __shfl_xor(s0[h], 16);
    s0[h] += __shfl_xor(s0[h], 32);
    s1[h] += __shfl_xor(s1[h], 16);
    s1[h] += __shfl_xor(s1[h], 32);
  }
  if (l < 16){
    atomicAdd(&sstat[r16],      s0[0]);
    atomicAdd(&sstat[32 + r16], s1[0]);
    atomicAdd(&sstat[16 + r16], s0[1]);
    atomicAdd(&sstat[48 + r16], s1[1]);
  }
  __syncthreads();
  if (tid < 64) atomicAdd(&stats[(blockIdx.x & 63)*64 + tid], sstat[tid]);
}

// ---- MFMA heads with inline final-BN; no block barriers (per-wave LDS only) ----
__global__ void __launch_bounds__(256) heads_mfma_kernel(
    const float* __restrict__ trunk, const float* __restrict__ stats,
    const float* __restrict__ gf, const float* __restrict__ bf,
    const unsigned short* __restrict__ pwh, const float* __restrict__ bcat,
    const float* __restrict__ b_le, const float* __restrict__ w_lr, const float* __restrict__ b_lr,
    float* __restrict__ out){
  __shared__ float lds[4][16][33];
  __shared__ float sbnp[64];
  int tid = threadIdx.x;
  if (tid < 32){
    float s = 0.f, q = 0.f;
    #pragma unroll
    for (int i = 0; i < 64; ++i){ s += stats[i*64 + tid]; q += stats[i*64 + 32 + tid]; }
    float inv = 1.0f / (float)NVOX;
    float mu  = s * inv;
    float var = q * inv - mu*mu;
    float sc  = gf[tid] * rsqrtf(var + 1e-4f);
    sbnp[tid]      = sc;
    sbnp[32 + tid] = bf[tid] - mu*sc;
  }
  __syncthreads();

  int l = tid & 63, w = tid >> 6;
  int g = l >> 4, r16 = l & 15;
  int base = blockIdx.x*256 + w*64;

  bf16x8 B1[6], B2[2];
  #pragma unroll
  for (int f = 0; f < 6; ++f)
    B1[f] = *reinterpret_cast<const bf16x8*>(pwh + f*512 + l*8);
  #pragma unroll
  for (int h = 0; h < 2; ++h)
    B2[h] = *reinterpret_cast<const bf16x8*>(pwh + (6+h)*512 + l*8);

  float sc[8], bi[8];
  #pragma unroll
  for (int i = 0; i < 8; ++i){ sc[i] = sbnp[g*8 + i]; bi[i] = sbnp[32 + g*8 + i]; }
  float wlr0 = w_lr[r16], wlr1 = w_lr[16 + r16];
  float blr  = b_lr[0];
  float bc0  = bcat[r16],      bc1  = bcat[16 + r16];   // b_fe
  float bc2  = bcat[32 + r16], bc3  = bcat[48 + r16];   // b_fr
  float bc4  = bcat[64 + r16], bc5  = bcat[80 + r16];   // b_cls (padded)
  float ble0 = b_le[r16],      ble1 = b_le[16 + r16];

  float* out_e = out + (size_t)NVOX*20;
  float* out_o = out + (size_t)NVOX*52;

  for (int t = 0; t < 4; ++t){
    int arow = base + t*16 + r16;
    f32x4 fa = {0.f,0.f,0.f,0.f}, fb2 = {0.f,0.f,0.f,0.f};
    if (arow < NVOX){
      const f32x4* p = reinterpret_cast<const f32x4*>(trunk + (size_t)arow*32 + g*8);
      fa  = __builtin_nontemporal_load(p);
      fb2 = __builtin_nontemporal_load(p + 1);
    }
    ushort8 au;
    au[0] = f2bf(fmaxf(fa.x*sc[0] + bi[0], 0.f));
    au[1] = f2bf(fmaxf(fa.y*sc[1] + bi[1], 0.f));
    au[2] = f2bf(fmaxf(fa.z*sc[2] + bi[2], 0.f));
    au[3] = f2bf(fmaxf(fa.w*sc[3] + bi[3], 0.f));
    au[4] = f2bf(fmaxf(fb2.x*sc[4] + bi[4], 0.f));
    au[5] = f2bf(fmaxf(fb2.y*sc[5] + bi[5], 0.f));
    au[6] = f2bf(fmaxf(fb2.z*sc[6] + bi[6], 0.f));
    au[7] = f2bf(fmaxf(fb2.w*sc[7] + bi[7], 0.f));
    bf16x8 a = __builtin_bit_cast(bf16x8, au);

    f32x4 acc[6];
    #pragma unroll
    for (int j = 0; j < 6; ++j){
      acc[j] = (f32x4){0.f,0.f,0.f,0.f};
      acc[j] = __builtin_amdgcn_mfma_f32_16x16x32_bf16(a, B1[j], acc[j], 0, 0, 0);
    }

    #pragma unroll
    for (int r = 0; r < 4; ++r){
      int orow = base + t*16 + g*4 + r;
      if (orow < NVOX){
        out[(size_t)orow*20 + r16] = acc[4][r] + bc4;           // cls 0..15
        if (r16 < 4)
          out[(size_t)orow*20 + 16 + r16] = acc[5][r] + bc5;    // cls 16..19
      }
    }

    float part[4];
    #pragma unroll
    for (int r = 0; r < 4; ++r)
      part[r] = (acc[2][r] + bc2)*wlr0 + (acc[3][r] + bc3)*wlr1;
    #pragma unroll
    for (int r = 0; r < 4; ++r){
      part[r] += __shfl_xor(part[r], 1);
      part[r] += __shfl_xor(part[r], 2);
      part[r] += __shfl_xor(part[r], 4);
      part[r] += __shfl_xor(part[r], 8);
    }
    if (r16 == 0){
      #pragma unroll
      for (int r = 0; r < 4; ++r){
        int orow = base + t*16 + g*4 + r;
        if (orow < NVOX)
          out_o[orow] = 1.f/(1.f + __expf(-(part[r] + blr)));
      }
    }

    // per-wave LDS repack (wave-internal: no block barrier needed)
    #pragma unroll
    for (int r = 0; r < 4; ++r){
      lds[w][g*4 + r][r16]      = acc[0][r] + bc0;
      lds[w][g*4 + r][16 + r16] = acc[1][r] + bc1;
    }
    ushort8 a2u;
    #pragma unroll
    for (int i = 0; i < 8; ++i)
      a2u[i] = f2bf(lds[w][r16][g*8 + i]);
    bf16x8 a2 = __builtin_bit_cast(bf16x8, a2u);
    f32x4 e0 = (f32x4){0.f,0.f,0.f,0.f}, e1 = (f32x4){0.f,0.f,0.f,0.f};
    e0 = __builtin_amdgcn_mfma_f32_16x16x32_bf16(a2, B2[0], e0, 0, 0, 0);
    e1 = __builtin_amdgcn_mfma_f32_16x16x32_bf16(a2, B2[1], e1, 0, 0, 0);
    #pragma unroll
    for (int r = 0; r < 4; ++r){
      int orow = base + t*16 + g*4 + r;
      if (orow < NVOX){
        out_e[(size_t)orow*32 + r16]      = e0[r] + ble0;
        out_e[(size_t)orow*32 + 16 + r16] = e1[r] + ble1;
      }
    }
  }
}

extern "C" void kernel_launch(void* const* d_in, const int* in_sizes, int n_in,
                              void* d_out, int out_size, void* d_ws, size_t ws_size,
                              hipStream_t stream){
  const float* features = (const float*)d_in[0];
  const int*   nbr      = (const int*)  d_in[1];
  const float* w0       = (const float*)d_in[2];
  const float* bw       = (const float*)d_in[3];
  const float* bg       = (const float*)d_in[4];
  const float* bb       = (const float*)d_in[5];
  const float* gf       = (const float*)d_in[6];
  const float* bf       = (const float*)d_in[7];
  const float* w_cls    = (const float*)d_in[8];
  const float* b_cls    = (const float*)d_in[9];
  const float* w_fe     = (const float*)d_in[10];
  const float* b_fe     = (const float*)d_in[11];
  const float* w_le     = (const float*)d_in[12];
  const float* b_le     = (const float*)d_in[13];
  const float* w_fr     = (const float*)d_in[14];
  const float* b_fr     = (const float*)d_in[15];
  const float* w_lr     = (const float*)d_in[16];
  const float* b_lr     = (const float*)d_in[17];
  float* out = (float*)d_out;

  char* ws = (char*)d_ws;
  float*          trunkA = (float*)(ws);                       // [N][32] f32
  float*          trunkH = (float*)(ws + 38400000);            // [N][32] f32
  f32x4*          fpad   = (f32x4*)(ws + 38400000);            // [N+1][4] f32 (dead before conv1 writes trunkH)
  unsigned short* actB   = (unsigned short*)(ws + 76800000);   // [(N+1)][32] bf16
  unsigned short* pw     = (unsigned short*)(ws + 96000128);   // packed conv weights (221184 B)
  unsigned short* pw0    = (unsigned short*)(ws + 96221312);   // packed conv0 weights (8192 B)
  float*          stats  = (float*)(ws + 96229504);            // 5 x 64 slots x 64 (81920 B)
  unsigned short* pwh    = (unsigned short*)(ws + 96311424);   // packed head weights (8192 B)
  float*          bcat   = (float*)(ws + 96319616);            // 96 f32 head biases

  hipMemsetAsync(stats, 0, 5*64*64*sizeof(float), stream);
  pack_w_kernel<<<(4*K27*2*64 + 4*2*64 + 255)/256, 256, 0, stream>>>(bw, w0, pw, pw0);
  pack_hw_kernel<<<1, 512, 0, stream>>>(w_cls, b_cls, w_fe, b_fe, w_le, w_fr, b_fr, pwh, bcat);
  prepad_kernel<<<(NVOX + 256)/256, 256, 0, stream>>>(features, fpad);

  const int NB  = (NVOX + 255)/256;
  const int NA  = ((NVOX+1)*4 + 255)/256;

  conv0_mfma_kernel<<<NBLK0, 256, 0, stream>>>(fpad, nbr, pw0, trunkA, stats + 0*4096);
  act_kernel<<<NA, 256, 0, stream>>>(trunkA, stats + 0*4096, bg +  0, bb +  0, actB);
  conv_mfma_kernel<false><<<NBLK, 256, 0, stream>>>(actB, nbr, pw + 0*27648, trunkH, stats + 1*4096);
  act_kernel<<<NA, 256, 0, stream>>>(trunkH, stats + 1*4096, bg + 32, bb + 32, actB);
  conv_mfma_kernel<true ><<<NBLK, 256, 0, stream>>>(actB, nbr, pw + 1*27648, trunkA, stats + 2*4096);
  act_kernel<<<NA, 256, 0, stream>>>(trunkA, stats + 2*4096, bg + 64, bb + 64, actB);
  conv_mfma_kernel<false><<<NBLK, 256, 0, stream>>>(actB, nbr, pw + 2*27648, trunkH, stats + 3*4096);
  act_kernel<<<NA, 256, 0, stream>>>(trunkH, stats + 3*4096, bg + 96, bb + 96, actB);
  conv_mfma_kernel<true ><<<NBLK, 256, 0, stream>>>(actB, nbr, pw + 3*27648, trunkA, stats + 4*4096);
  heads_mfma_kernel<<<NB, 256, 0, stream>>>(trunkA, stats + 4*4096, gf, bf, pwh, bcat,
                                            b_le, w_lr, b_lr, out);
}

// Round 11
// 450.714 us; speedup vs baseline: 1.2173x; 1.2173x over previous
//
#include <hip/hip_runtime.h>

#define NVOX 300000
#define K27 27
#define VPB 128           // voxels per block (4 waves x 32)
#define TILES 2           // 16-row MFMA tiles per wave
#define NBLK 2344         // = ceil(NVOX/VPB), divisible by 8
#define CPX  (NBLK/8)     // chunks per XCD

typedef __attribute__((ext_vector_type(8))) __bf16 bf16x8;
typedef __attribute__((ext_vector_type(8))) unsigned short ushort8;
typedef __attribute__((ext_vector_type(4))) float f32x4;

__device__ inline unsigned short f2bf(float x){
  unsigned int u = __float_as_uint(x);
  unsigned int r = (u + 0x7FFFu + ((u >> 16) & 1u)) >> 16;   // RNE
  return (unsigned short)r;
}

// ---- pack conv weights ----
__global__ void pack_w_kernel(const float* __restrict__ bw, const float* __restrict__ w0,
                              unsigned short* __restrict__ pw, unsigned short* __restrict__ pw0){
  int t = blockIdx.x*256 + threadIdx.x;
  if (t < 4*K27*2*64){
    int l  = t & 63;
    int h  = (t >> 6) & 1;
    int k  = (t >> 7) % K27;
    int cv = t / (128*K27);
    int g = l >> 4, r16 = l & 15;
    ushort8 o;
    #pragma unroll
    for (int i = 0; i < 8; ++i){
      int c  = g*8 + i;
      int oc = h*16 + r16;
      o[i] = f2bf(bw[(((cv*K27 + k)*32) + c)*32 + oc]);
    }
    *reinterpret_cast<ushort8*>(pw + t*8) = o;
    return;
  }
  int u = t - 4*K27*2*64;
  if (u >= 4*2*64) return;
  int l  = u & 63;
  int h  = (u >> 6) & 1;
  int kb = u >> 7;
  int g = l >> 4, r16 = l & 15;
  int col = h*16 + r16;
  ushort8 o;
  #pragma unroll
  for (int i = 0; i < 8; ++i){
    int k   = kb*32 + g*8 + i;
    int tap = k >> 2, ch = k & 3;
    float v = (tap < K27 && ch < 3) ? w0[(tap*3 + ch)*32 + col] : 0.f;
    o[i] = f2bf(v);
  }
  *reinterpret_cast<ushort8*>(pw0 + u*8) = o;
}

// ---- pack head weights ----
__global__ void pack_hw_kernel(const float* __restrict__ w_cls, const float* __restrict__ b_cls,
                               const float* __restrict__ w_fe,  const float* __restrict__ b_fe,
                               const float* __restrict__ w_le,
                               const float* __restrict__ w_fr,  const float* __restrict__ b_fr,
                               unsigned short* __restrict__ pwh, float* __restrict__ bcat){
  int t = blockIdx.x*512 + threadIdx.x;
  if (t < 96){
    float v = 0.f;
    if (t < 32)      v = b_fe[t];
    else if (t < 64) v = b_fr[t-32];
    else if (t < 84) v = b_cls[t-64];
    bcat[t] = v;
  }
  if (t >= 8*64) return;
  int l = t & 63, f = t >> 6;
  int g = l >> 4, r16 = l & 15;
  ushort8 o;
  #pragma unroll
  for (int i = 0; i < 8; ++i){
    int k = g*8 + i;
    float v;
    if (f < 6){
      int col = f*16 + r16;
      if (col < 32)      v = w_fe[k*32 + col];
      else if (col < 64) v = w_fr[k*32 + (col-32)];
      else { int c = col - 64; v = (c < 20) ? w_cls[k*20 + c] : 0.f; }
    } else {
      int col = (f-6)*16 + r16;
      v = w_le[k*32 + col];
    }
    o[i] = f2bf(v);
  }
  *reinterpret_cast<ushort8*>(pwh + t*8) = o;
}

// ---- pre-pad features: [N,3] f32 -> [N+1][4] f32 (w=0, row N = 0 sentinel) ----
__global__ void prepad_kernel(const float* __restrict__ feats, f32x4* __restrict__ fpad){
  int row = blockIdx.x*256 + threadIdx.x;
  if (row > NVOX) return;
  f32x4 v = {0.f, 0.f, 0.f, 0.f};
  if (row < NVOX){
    v.x = feats[row*3+0]; v.y = feats[row*3+1]; v.z = feats[row*3+2];
  }
  fpad[row] = v;
}

// ---- conv0 via MFMA: K=108 (27 taps x 4ch padded) ----
__global__ void __launch_bounds__(256) conv0_mfma_kernel(
    const f32x4* __restrict__ fpad, const int* __restrict__ nbr,
    const unsigned short* __restrict__ pw0, float* __restrict__ trunk,
    float* __restrict__ stats){
  __shared__ int   snbr[256*K27];
  __shared__ float sstat[64];
  int tid  = threadIdx.x;
  int base = blockIdx.x*256;
  for (int i = tid; i < 256*K27; i += 256){
    int v = base + i / K27;
    snbr[i] = (v < NVOX) ? nbr[(size_t)base*K27 + i] : NVOX;
  }
  if (tid < 64) sstat[tid] = 0.f;
  __syncthreads();

  int l = tid & 63, w = tid >> 6;
  int g = l >> 4, r16 = l & 15;
  const int vb = w*64;

  bf16x8 B[4][2];
  #pragma unroll
  for (int kb = 0; kb < 4; ++kb)
    #pragma unroll
    for (int h = 0; h < 2; ++h)
      B[kb][h] = *reinterpret_cast<const bf16x8*>(pw0 + (kb*2 + h)*512 + l*8);

  f32x4 acc[4][2];
  #pragma unroll
  for (int t = 0; t < 4; ++t)
    #pragma unroll
    for (int h = 0; h < 2; ++h)
      acc[t][h] = (f32x4){0.f,0.f,0.f,0.f};

  #pragma unroll
  for (int t = 0; t < 4; ++t){
    int row = (vb + t*16 + r16)*K27;
    #pragma unroll
    for (int kb = 0; kb < 4; ++kb){
      int tap0 = kb*8 + g*2;
      int tap1 = tap0 + 1;
      int i0 = (tap0 < K27) ? tap0 : 0;
      int i1 = (tap1 < K27) ? tap1 : 0;
      int j0 = snbr[row + i0]; if (tap0 >= K27) j0 = NVOX;
      int j1 = snbr[row + i1]; if (tap1 >= K27) j1 = NVOX;
      f32x4 v0 = fpad[j0];
      f32x4 v1 = fpad[j1];
      ushort8 au;
      au[0] = f2bf(v0.x); au[1] = f2bf(v0.y); au[2] = f2bf(v0.z); au[3] = 0;
      au[4] = f2bf(v1.x); au[5] = f2bf(v1.y); au[6] = f2bf(v1.z); au[7] = 0;
      bf16x8 a = __builtin_bit_cast(bf16x8, au);
      acc[t][0] = __builtin_amdgcn_mfma_f32_16x16x32_bf16(a, B[kb][0], acc[t][0], 0, 0, 0);
      acc[t][1] = __builtin_amdgcn_mfma_f32_16x16x32_bf16(a, B[kb][1], acc[t][1], 0, 0, 0);
    }
  }

  float s0[2] = {0.f, 0.f}, s1[2] = {0.f, 0.f};
  #pragma unroll
  for (int t = 0; t < 4; ++t){
    #pragma unroll
    for (int r = 0; r < 4; ++r){
      int row = base + vb + t*16 + g*4 + r;
      if (row < NVOX){
        #pragma unroll
        for (int h = 0; h < 2; ++h){
          float v = acc[t][h][r];
          trunk[(size_t)row*32 + h*16 + r16] = v;
          s0[h] += v; s1[h] += v*v;
        }
      }
    }
  }
  #pragma unroll
  for (int h = 0; h < 2; ++h){
    s0[h] += __shfl_xor(s0[h], 16);
    s0[h] += __shfl_xor(s0[h], 32);
    s1[h] += __shfl_xor(s1[h], 16);
    s1[h] += __shfl_xor(s1[h], 32);
  }
  if (l < 16){
    atomicAdd(&sstat[r16],      s0[0]);
    atomicAdd(&sstat[32 + r16], s1[0]);
    atomicAdd(&sstat[16 + r16], s0[1]);
    atomicAdd(&sstat[48 + r16], s1[1]);
  }
  __syncthreads();
  if (tid < 64) atomicAdd(&stats[(blockIdx.x & 63)*64 + tid], sstat[tid]);
}

// ---- activation with inline BN finalize ----
__global__ void __launch_bounds__(256) act_kernel(
    const float* __restrict__ trunk, const float* __restrict__ stats,
    const float* __restrict__ g, const float* __restrict__ b,
    unsigned short* __restrict__ act){
  __shared__ float sbnp[64];
  int tid = threadIdx.x;
  if (tid < 32){
    float s = 0.f, q = 0.f;
    #pragma unroll
    for (int i = 0; i < 64; ++i){ s += stats[i*64 + tid]; q += stats[i*64 + 32 + tid]; }
    float inv = 1.0f / (float)NVOX;
    float mu  = s * inv;
    float var = q * inv - mu*mu;
    float sc  = g[tid] * rsqrtf(var + 1e-4f);
    sbnp[tid]      = sc;
    sbnp[32 + tid] = b[tid] - mu*sc;
  }
  __syncthreads();

  int t = blockIdx.x*256 + tid;
  if (t >= (NVOX+1)*4) return;
  int row = t >> 2, part = t & 3;
  ushort8 o;
  if (row < NVOX){
    const float* p = trunk + (size_t)row*32 + part*8;
    #pragma unroll
    for (int i = 0; i < 8; ++i){
      float v = p[i]*sbnp[part*8 + i] + sbnp[32 + part*8 + i];
      v = fmaxf(v, 0.f);
      o[i] = f2bf(v);
    }
  } else {
    #pragma unroll
    for (int i = 0; i < 8; ++i) o[i] = 0;
  }
  *reinterpret_cast<ushort8*>(act + (size_t)row*32 + part*8) = o;
}

// ---- MFMA conv 32->32; XCD-chunked swizzle only (no nt) ----
template<bool RES>
__global__ void __launch_bounds__(256) conv_mfma_kernel(
    const unsigned short* __restrict__ act, const int* __restrict__ nbr,
    const unsigned short* __restrict__ pw, float* __restrict__ trunk,
    float* __restrict__ stats){
  int bid   = blockIdx.x;
  int chunk = (bid & 7)*CPX + (bid >> 3);
  const int base = chunk*VPB;

  __shared__ int   snbr[VPB*K27];
  __shared__ float sstat[64];
  int tid = threadIdx.x;
  for (int i = tid; i < VPB*K27; i += 256){
    int v = base + i / K27;
    snbr[i] = (v < NVOX) ? nbr[(size_t)base*K27 + i] : NVOX;
  }
  if (tid < 64) sstat[tid] = 0.f;
  __syncthreads();

  int l = tid & 63, w = tid >> 6;
  int g = l >> 4, r16 = l & 15;
  const int vb = w*(TILES*16);

  int rb[TILES];
  #pragma unroll
  for (int t = 0; t < TILES; ++t) rb[t] = (vb + t*16 + r16)*K27;

  f32x4 acc[TILES][2];
  #pragma unroll
  for (int t = 0; t < TILES; ++t)
    #pragma unroll
    for (int h = 0; h < 2; ++h)
      acc[t][h] = (f32x4){0.f,0.f,0.f,0.f};

  #pragma unroll
  for (int k = 0; k < K27; ++k){
    bf16x8 b0 = *reinterpret_cast<const bf16x8*>(pw + (k*2    )*512 + l*8);
    bf16x8 b1 = *reinterpret_cast<const bf16x8*>(pw + (k*2 + 1)*512 + l*8);
    bf16x8 a[TILES];
    #pragma unroll
    for (int t = 0; t < TILES; ++t){
      int j = snbr[rb[t] + k];
      a[t] = *reinterpret_cast<const bf16x8*>(act + (size_t)j*32 + g*8);
    }
    #pragma unroll
    for (int t = 0; t < TILES; ++t){
      acc[t][0] = __builtin_amdgcn_mfma_f32_16x16x32_bf16(a[t], b0, acc[t][0], 0, 0, 0);
      acc[t][1] = __builtin_amdgcn_mfma_f32_16x16x32_bf16(a[t], b1, acc[t][1], 0, 0, 0);
    }
  }

  float s0[2] = {0.f, 0.f}, s1[2] = {0.f, 0.f};
  #pragma unroll
  for (int t = 0; t < TILES; ++t){
    #pragma unroll
    for (int r = 0; r < 4; ++r){
      int row = base + vb + t*16 + g*4 + r;
      if (row < NVOX){
        #pragma unroll
        for (int h = 0; h < 2; ++h){
          float v = acc[t][h][r];
          float* p = trunk + (size_t)row*32 + h*16 + r16;
          if (RES) v += *p;
          *p = v;
          s0[h] += v; s1[h] += v*v;
        }
      }
    }
  }
  #pragma unroll
  for (int h = 0; h < 2; ++h){
    s0[h] += __shfl_xor(s0[h], 16);
    s0[h] += __shfl_xor(s0[h], 32);
    s1[h] += __shfl_xor(s1[h], 16);
    s1[h] += __shfl_xor(s1[h], 32);
  }
  if (l < 16){
    atomicAdd(&sstat[r16],      s0[0]);
    atomicAdd(&sstat[32 + r16], s1[0]);
    atomicAdd(&sstat[16 + r16], s0[1]);
    atomicAdd(&sstat[48 + r16], s1[1]);
  }
  __syncthreads();
  if (tid < 64) atomicAdd(&stats[(blockIdx.x & 63)*64 + tid], sstat[tid]);
}

// ---- MFMA heads with inline final-BN; no block barriers (per-wave LDS only) ----
__global__ void __launch_bounds__(256) heads_mfma_kernel(
    const float* __restrict__ trunk, const float* __restrict__ stats,
    const float* __restrict__ gf, const float* __restrict__ bf,
    const unsigned short* __restrict__ pwh, const float* __restrict__ bcat,
    const float* __restrict__ b_le, const float* __restrict__ w_lr, const float* __restrict__ b_lr,
    float* __restrict__ out){
  __shared__ float lds[4][16][33];
  __shared__ float sbnp[64];
  int tid = threadIdx.x;
  if (tid < 32){
    float s = 0.f, q = 0.f;
    #pragma unroll
    for (int i = 0; i < 64; ++i){ s += stats[i*64 + tid]; q += stats[i*64 + 32 + tid]; }
    float inv = 1.0f / (float)NVOX;
    float mu  = s * inv;
    float var = q * inv - mu*mu;
    float sc  = gf[tid] * rsqrtf(var + 1e-4f);
    sbnp[tid]      = sc;
    sbnp[32 + tid] = bf[tid] - mu*sc;
  }
  __syncthreads();

  int l = tid & 63, w = tid >> 6;
  int g = l >> 4, r16 = l & 15;
  int base = blockIdx.x*256 + w*64;

  bf16x8 B1[6], B2[2];
  #pragma unroll
  for (int f = 0; f < 6; ++f)
    B1[f] = *reinterpret_cast<const bf16x8*>(pwh + f*512 + l*8);
  #pragma unroll
  for (int h = 0; h < 2; ++h)
    B2[h] = *reinterpret_cast<const bf16x8*>(pwh + (6+h)*512 + l*8);

  float sc[8], bi[8];
  #pragma unroll
  for (int i = 0; i < 8; ++i){ sc[i] = sbnp[g*8 + i]; bi[i] = sbnp[32 + g*8 + i]; }
  float wlr0 = w_lr[r16], wlr1 = w_lr[16 + r16];
  float blr  = b_lr[0];
  float bc0  = bcat[r16],      bc1  = bcat[16 + r16];   // b_fe
  float bc2  = bcat[32 + r16], bc3  = bcat[48 + r16];   // b_fr
  float bc4  = bcat[64 + r16], bc5  = bcat[80 + r16];   // b_cls (padded)
  float ble0 = b_le[r16],      ble1 = b_le[16 + r16];

  float* out_e = out + (size_t)NVOX*20;
  float* out_o = out + (size_t)NVOX*52;

  for (int t = 0; t < 4; ++t){
    int arow = base + t*16 + r16;
    f32x4 fa = {0.f,0.f,0.f,0.f}, fb2 = {0.f,0.f,0.f,0.f};
    if (arow < NVOX){
      const f32x4* p = reinterpret_cast<const f32x4*>(trunk + (size_t)arow*32 + g*8);
      fa  = p[0];
      fb2 = p[1];
    }
    ushort8 au;
    au[0] = f2bf(fmaxf(fa.x*sc[0] + bi[0], 0.f));
    au[1] = f2bf(fmaxf(fa.y*sc[1] + bi[1], 0.f));
    au[2] = f2bf(fmaxf(fa.z*sc[2] + bi[2], 0.f));
    au[3] = f2bf(fmaxf(fa.w*sc[3] + bi[3], 0.f));
    au[4] = f2bf(fmaxf(fb2.x*sc[4] + bi[4], 0.f));
    au[5] = f2bf(fmaxf(fb2.y*sc[5] + bi[5], 0.f));
    au[6] = f2bf(fmaxf(fb2.z*sc[6] + bi[6], 0.f));
    au[7] = f2bf(fmaxf(fb2.w*sc[7] + bi[7], 0.f));
    bf16x8 a = __builtin_bit_cast(bf16x8, au);

    f32x4 acc[6];
    #pragma unroll
    for (int j = 0; j < 6; ++j){
      acc[j] = (f32x4){0.f,0.f,0.f,0.f};
      acc[j] = __builtin_amdgcn_mfma_f32_16x16x32_bf16(a, B1[j], acc[j], 0, 0, 0);
    }

    #pragma unroll
    for (int r = 0; r < 4; ++r){
      int orow = base + t*16 + g*4 + r;
      if (orow < NVOX){
        out[(size_t)orow*20 + r16] = acc[4][r] + bc4;           // cls 0..15
        if (r16 < 4)
          out[(size_t)orow*20 + 16 + r16] = acc[5][r] + bc5;    // cls 16..19
      }
    }

    float part[4];
    #pragma unroll
    for (int r = 0; r < 4; ++r)
      part[r] = (acc[2][r] + bc2)*wlr0 + (acc[3][r] + bc3)*wlr1;
    #pragma unroll
    for (int r = 0; r < 4; ++r){
      part[r] += __shfl_xor(part[r], 1);
      part[r] += __shfl_xor(part[r], 2);
      part[r] += __shfl_xor(part[r], 4);
      part[r] += __shfl_xor(part[r], 8);
    }
    if (r16 == 0){
      #pragma unroll
      for (int r = 0; r < 4; ++r){
        int orow = base + t*16 + g*4 + r;
        if (orow < NVOX)
          out_o[orow] = 1.f/(1.f + __expf(-(part[r] + blr)));
      }
    }

    // per-wave LDS repack (wave-internal: no block barrier needed)
    #pragma unroll
    for (int r = 0; r < 4; ++r){
      lds[w][g*4 + r][r16]      = acc[0][r] + bc0;
      lds[w][g*4 + r][16 + r16] = acc[1][r] + bc1;
    }
    ushort8 a2u;
    #pragma unroll
    for (int i = 0; i < 8; ++i)
      a2u[i] = f2bf(lds[w][r16][g*8 + i]);
    bf16x8 a2 = __builtin_bit_cast(bf16x8, a2u);
    f32x4 e0 = (f32x4){0.f,0.f,0.f,0.f}, e1 = (f32x4){0.f,0.f,0.f,0.f};
    e0 = __builtin_amdgcn_mfma_f32_16x16x32_bf16(a2, B2[0], e0, 0, 0, 0);
    e1 = __builtin_amdgcn_mfma_f32_16x16x32_bf16(a2, B2[1], e1, 0, 0, 0);
    #pragma unroll
    for (int r = 0; r < 4; ++r){
      int orow = base + t*16 + g*4 + r;
      if (orow < NVOX){
        out_e[(size_t)orow*32 + r16]      = e0[r] + ble0;
        out_e[(size_t)orow*32 + 16 + r16] = e1[r] + ble1;
      }
    }
  }
}

extern "C" void kernel_launch(void* const* d_in, const int* in_sizes, int n_in,
                              void* d_out, int out_size, void* d_ws, size_t ws_size,
                              hipStream_t stream){
  const float* features = (const float*)d_in[0];
  const int*   nbr      = (const int*)  d_in[1];
  const float* w0       = (const float*)d_in[2];
  const float* bw       = (const float*)d_in[3];
  const float* bg       = (const float*)d_in[4];
  const float* bb       = (const float*)d_in[5];
  const float* gf       = (const float*)d_in[6];
  const float* bf       = (const float*)d_in[7];
  const float* w_cls    = (const float*)d_in[8];
  const float* b_cls    = (const float*)d_in[9];
  const float* w_fe     = (const float*)d_in[10];
  const float* b_fe     = (const float*)d_in[11];
  const float* w_le     = (const float*)d_in[12];
  const float* b_le     = (const float*)d_in[13];
  const float* w_fr     = (const float*)d_in[14];
  const float* b_fr     = (const float*)d_in[15];
  const float* w_lr     = (const float*)d_in[16];
  const float* b_lr     = (const float*)d_in[17];
  float* out = (float*)d_out;

  char* ws = (char*)d_ws;
  float*          trunkA = (float*)(ws);                       // [N][32] f32
  float*          trunkH = (float*)(ws + 38400000);            // [N][32] f32
  f32x4*          fpad   = (f32x4*)(ws + 38400000);            // [N+1][4] f32 (dead before conv1 writes trunkH)
  unsigned short* actB   = (unsigned short*)(ws + 76800000);   // [(N+1)][32] bf16
  unsigned short* pw     = (unsigned short*)(ws + 96000128);   // packed conv weights (221184 B)
  unsigned short* pw0    = (unsigned short*)(ws + 96221312);   // packed conv0 weights (8192 B)
  float*          stats  = (float*)(ws + 96229504);            // 5 x 64 slots x 64 (81920 B)
  unsigned short* pwh    = (unsigned short*)(ws + 96311424);   // packed head weights (8192 B)
  float*          bcat   = (float*)(ws + 96319616);            // 96 f32 head biases

  hipMemsetAsync(stats, 0, 5*64*64*sizeof(float), stream);
  pack_w_kernel<<<(4*K27*2*64 + 4*2*64 + 255)/256, 256, 0, stream>>>(bw, w0, pw, pw0);
  pack_hw_kernel<<<1, 512, 0, stream>>>(w_cls, b_cls, w_fe, b_fe, w_le, w_fr, b_fr, pwh, bcat);
  prepad_kernel<<<(NVOX + 256)/256, 256, 0, stream>>>(features, fpad);

  const int NB  = (NVOX + 255)/256;
  const int NA  = ((NVOX+1)*4 + 255)/256;

  conv0_mfma_kernel<<<NB, 256, 0, stream>>>(fpad, nbr, pw0, trunkA, stats + 0*4096);
  act_kernel<<<NA, 256, 0, stream>>>(trunkA, stats + 0*4096, bg +  0, bb +  0, actB);
  conv_mfma_kernel<false><<<NBLK, 256, 0, stream>>>(actB, nbr, pw + 0*27648, trunkH, stats + 1*4096);
  act_kernel<<<NA, 256, 0, stream>>>(trunkH, stats + 1*4096, bg + 32, bb + 32, actB);
  conv_mfma_kernel<true ><<<NBLK, 256, 0, stream>>>(actB, nbr, pw + 1*27648, trunkA, stats + 2*4096);
  act_kernel<<<NA, 256, 0, stream>>>(trunkA, stats + 2*4096, bg + 64, bb + 64, actB);
  conv_mfma_kernel<false><<<NBLK, 256, 0, stream>>>(actB, nbr, pw + 2*27648, trunkH, stats + 3*4096);
  act_kernel<<<NA, 256, 0, stream>>>(trunkH, stats + 3*4096, bg + 96, bb + 96, actB);
  conv_mfma_kernel<true ><<<NBLK, 256, 0, stream>>>(actB, nbr, pw + 3*27648, trunkA, stats + 4*4096);
  heads_mfma_kernel<<<NB, 256, 0, stream>>>(trunkA, stats + 4*4096, gf, bf, pwh, bcat,
                                            b_le, w_lr, b_lr, out);
}

// Round 12
// 444.775 us; speedup vs baseline: 1.2336x; 1.0134x over previous
//
#include <hip/hip_runtime.h>

#define NVOX 300000
#define K27 27
#define VPB 128           // voxels per block
#define TILES 2           // 16-row MFMA tiles per wave
#define NBLK 2344         // = ceil(NVOX/VPB), divisible by 8
#define CPX  (NBLK/8)     // chunks per XCD

typedef __attribute__((ext_vector_type(8))) __bf16 bf16x8;
typedef __attribute__((ext_vector_type(8))) unsigned short ushort8;
typedef __attribute__((ext_vector_type(4))) float f32x4;

__device__ inline unsigned short f2bf(float x){
  unsigned int u = __float_as_uint(x);
  unsigned int r = (u + 0x7FFFu + ((u >> 16) & 1u)) >> 16;   // RNE
  return (unsigned short)r;
}

// ---- pack conv weights ----
__global__ void pack_w_kernel(const float* __restrict__ bw, const float* __restrict__ w0,
                              unsigned short* __restrict__ pw, unsigned short* __restrict__ pw0){
  int t = blockIdx.x*256 + threadIdx.x;
  if (t < 4*K27*2*64){
    int l  = t & 63;
    int h  = (t >> 6) & 1;
    int k  = (t >> 7) % K27;
    int cv = t / (128*K27);
    int g = l >> 4, r16 = l & 15;
    ushort8 o;
    #pragma unroll
    for (int i = 0; i < 8; ++i){
      int c  = g*8 + i;
      int oc = h*16 + r16;
      o[i] = f2bf(bw[(((cv*K27 + k)*32) + c)*32 + oc]);
    }
    *reinterpret_cast<ushort8*>(pw + t*8) = o;
    return;
  }
  int u = t - 4*K27*2*64;
  if (u >= 4*2*64) return;
  int l  = u & 63;
  int h  = (u >> 6) & 1;
  int kb = u >> 7;
  int g = l >> 4, r16 = l & 15;
  int col = h*16 + r16;
  ushort8 o;
  #pragma unroll
  for (int i = 0; i < 8; ++i){
    int k   = kb*32 + g*8 + i;
    int tap = k >> 2, ch = k & 3;
    float v = (tap < K27 && ch < 3) ? w0[(tap*3 + ch)*32 + col] : 0.f;
    o[i] = f2bf(v);
  }
  *reinterpret_cast<ushort8*>(pw0 + u*8) = o;
}

// ---- pack head weights ----
__global__ void pack_hw_kernel(const float* __restrict__ w_cls, const float* __restrict__ b_cls,
                               const float* __restrict__ w_fe,  const float* __restrict__ b_fe,
                               const float* __restrict__ w_le,
                               const float* __restrict__ w_fr,  const float* __restrict__ b_fr,
                               unsigned short* __restrict__ pwh, float* __restrict__ bcat){
  int t = blockIdx.x*512 + threadIdx.x;
  if (t < 96){
    float v = 0.f;
    if (t < 32)      v = b_fe[t];
    else if (t < 64) v = b_fr[t-32];
    else if (t < 84) v = b_cls[t-64];
    bcat[t] = v;
  }
  if (t >= 8*64) return;
  int l = t & 63, f = t >> 6;
  int g = l >> 4, r16 = l & 15;
  ushort8 o;
  #pragma unroll
  for (int i = 0; i < 8; ++i){
    int k = g*8 + i;
    float v;
    if (f < 6){
      int col = f*16 + r16;
      if (col < 32)      v = w_fe[k*32 + col];
      else if (col < 64) v = w_fr[k*32 + (col-32)];
      else { int c = col - 64; v = (c < 20) ? w_cls[k*20 + c] : 0.f; }
    } else {
      int col = (f-6)*16 + r16;
      v = w_le[k*32 + col];
    }
    o[i] = f2bf(v);
  }
  *reinterpret_cast<ushort8*>(pwh + t*8) = o;
}

// ---- pre-pad features: [N,3] f32 -> [N+1][4] f32 (w=0, row N = 0 sentinel) ----
__global__ void prepad_kernel(const float* __restrict__ feats, f32x4* __restrict__ fpad){
  int row = blockIdx.x*256 + threadIdx.x;
  if (row > NVOX) return;
  f32x4 v = {0.f, 0.f, 0.f, 0.f};
  if (row < NVOX){
    v.x = feats[row*3+0]; v.y = feats[row*3+1]; v.z = feats[row*3+2];
  }
  fpad[row] = v;
}

// ---- conv0 via MFMA: K=108 (27 taps x 4ch padded) ----
__global__ void __launch_bounds__(256) conv0_mfma_kernel(
    const f32x4* __restrict__ fpad, const int* __restrict__ nbr,
    const unsigned short* __restrict__ pw0, float* __restrict__ trunk,
    float* __restrict__ stats){
  __shared__ int   snbr[256*K27];
  __shared__ float sstat[64];
  int tid  = threadIdx.x;
  int base = blockIdx.x*256;
  for (int i = tid; i < 256*K27; i += 256){
    int v = base + i / K27;
    snbr[i] = (v < NVOX) ? nbr[(size_t)base*K27 + i] : NVOX;
  }
  if (tid < 64) sstat[tid] = 0.f;
  __syncthreads();

  int l = tid & 63, w = tid >> 6;
  int g = l >> 4, r16 = l & 15;
  const int vb = w*64;

  bf16x8 B[4][2];
  #pragma unroll
  for (int kb = 0; kb < 4; ++kb)
    #pragma unroll
    for (int h = 0; h < 2; ++h)
      B[kb][h] = *reinterpret_cast<const bf16x8*>(pw0 + (kb*2 + h)*512 + l*8);

  f32x4 acc[4][2];
  #pragma unroll
  for (int t = 0; t < 4; ++t)
    #pragma unroll
    for (int h = 0; h < 2; ++h)
      acc[t][h] = (f32x4){0.f,0.f,0.f,0.f};

  #pragma unroll
  for (int t = 0; t < 4; ++t){
    int row = (vb + t*16 + r16)*K27;
    #pragma unroll
    for (int kb = 0; kb < 4; ++kb){
      int tap0 = kb*8 + g*2;
      int tap1 = tap0 + 1;
      int i0 = (tap0 < K27) ? tap0 : 0;
      int i1 = (tap1 < K27) ? tap1 : 0;
      int j0 = snbr[row + i0]; if (tap0 >= K27) j0 = NVOX;
      int j1 = snbr[row + i1]; if (tap1 >= K27) j1 = NVOX;
      f32x4 v0 = fpad[j0];
      f32x4 v1 = fpad[j1];
      ushort8 au;
      au[0] = f2bf(v0.x); au[1] = f2bf(v0.y); au[2] = f2bf(v0.z); au[3] = 0;
      au[4] = f2bf(v1.x); au[5] = f2bf(v1.y); au[6] = f2bf(v1.z); au[7] = 0;
      bf16x8 a = __builtin_bit_cast(bf16x8, au);
      acc[t][0] = __builtin_amdgcn_mfma_f32_16x16x32_bf16(a, B[kb][0], acc[t][0], 0, 0, 0);
      acc[t][1] = __builtin_amdgcn_mfma_f32_16x16x32_bf16(a, B[kb][1], acc[t][1], 0, 0, 0);
    }
  }

  float s0[2] = {0.f, 0.f}, s1[2] = {0.f, 0.f};
  #pragma unroll
  for (int t = 0; t < 4; ++t){
    #pragma unroll
    for (int r = 0; r < 4; ++r){
      int row = base + vb + t*16 + g*4 + r;
      if (row < NVOX){
        #pragma unroll
        for (int h = 0; h < 2; ++h){
          float v = acc[t][h][r];
          trunk[(size_t)row*32 + h*16 + r16] = v;
          s0[h] += v; s1[h] += v*v;
        }
      }
    }
  }
  #pragma unroll
  for (int h = 0; h < 2; ++h){
    s0[h] += __shfl_xor(s0[h], 16);
    s0[h] += __shfl_xor(s0[h], 32);
    s1[h] += __shfl_xor(s1[h], 16);
    s1[h] += __shfl_xor(s1[h], 32);
  }
  if (l < 16){
    atomicAdd(&sstat[r16],      s0[0]);
    atomicAdd(&sstat[32 + r16], s1[0]);
    atomicAdd(&sstat[16 + r16], s0[1]);
    atomicAdd(&sstat[48 + r16], s1[1]);
  }
  __syncthreads();
  if (tid < 64) atomicAdd(&stats[(blockIdx.x & 63)*64 + tid], sstat[tid]);
}

// ---- activation with inline BN finalize ----
__global__ void __launch_bounds__(256) act_kernel(
    const float* __restrict__ trunk, const float* __restrict__ stats,
    const float* __restrict__ g, const float* __restrict__ b,
    unsigned short* __restrict__ act){
  __shared__ float sbnp[64];
  int tid = threadIdx.x;
  if (tid < 32){
    float s = 0.f, q = 0.f;
    #pragma unroll
    for (int i = 0; i < 64; ++i){ s += stats[i*64 + tid]; q += stats[i*64 + 32 + tid]; }
    float inv = 1.0f / (float)NVOX;
    float mu  = s * inv;
    float var = q * inv - mu*mu;
    float sc  = g[tid] * rsqrtf(var + 1e-4f);
    sbnp[tid]      = sc;
    sbnp[32 + tid] = b[tid] - mu*sc;
  }
  __syncthreads();

  int t = blockIdx.x*256 + tid;
  if (t >= (NVOX+1)*4) return;
  int row = t >> 2, part = t & 3;
  ushort8 o;
  if (row < NVOX){
    const float* p = trunk + (size_t)row*32 + part*8;
    #pragma unroll
    for (int i = 0; i < 8; ++i){
      float v = p[i]*sbnp[part*8 + i] + sbnp[32 + part*8 + i];
      v = fmaxf(v, 0.f);
      o[i] = f2bf(v);
    }
  } else {
    #pragma unroll
    for (int i = 0; i < 8; ++i) o[i] = 0;
  }
  *reinterpret_cast<ushort8*>(act + (size_t)row*32 + part*8) = o;
}

// ---- MFMA conv 32->32; K-split over 8 waves (waves 0-3: taps 0-13, waves 4-7: taps 14-26);
//      XCD-chunked swizzle; LDS partial-sum combine ----
template<bool RES>
__global__ void __launch_bounds__(512) conv_mfma_kernel(
    const unsigned short* __restrict__ act, const int* __restrict__ nbr,
    const unsigned short* __restrict__ pw, float* __restrict__ trunk,
    float* __restrict__ stats){
  int bid   = blockIdx.x;
  int chunk = (bid & 7)*CPX + (bid >> 3);
  const int base = chunk*VPB;

  __shared__ int   snbr[VPB*K27];        // 13824 B
  __shared__ float sacc[16][4][64];      // 16384 B: [reg_idx][vw][lane], stride-1 in lane
  __shared__ float sstat[64];
  int tid = threadIdx.x;
  for (int i = tid; i < VPB*K27; i += 512){
    int v = base + i / K27;
    snbr[i] = (v < NVOX) ? nbr[(size_t)base*K27 + i] : NVOX;
  }
  if (tid < 64) sstat[tid] = 0.f;
  __syncthreads();

  int l = tid & 63, w = tid >> 6;        // w in [0,8)
  int vw = w & 3, half = w >> 2;
  int g = l >> 4, r16 = l & 15;
  const int vb = vw*(TILES*16);

  const int rb0 = (vb      + r16)*K27;
  const int rb1 = (vb + 16 + r16)*K27;

  f32x4 acc[TILES][2];
  #pragma unroll
  for (int t = 0; t < TILES; ++t)
    #pragma unroll
    for (int h = 0; h < 2; ++h)
      acc[t][h] = (f32x4){0.f,0.f,0.f,0.f};

#define KSTEP(kk) { \
    bf16x8 b0 = *reinterpret_cast<const bf16x8*>(pw + ((kk)*2    )*512 + l*8); \
    bf16x8 b1 = *reinterpret_cast<const bf16x8*>(pw + ((kk)*2 + 1)*512 + l*8); \
    int j0 = snbr[rb0 + (kk)], j1 = snbr[rb1 + (kk)]; \
    bf16x8 a0 = *reinterpret_cast<const bf16x8*>(act + (size_t)j0*32 + g*8); \
    bf16x8 a1 = *reinterpret_cast<const bf16x8*>(act + (size_t)j1*32 + g*8); \
    acc[0][0] = __builtin_amdgcn_mfma_f32_16x16x32_bf16(a0, b0, acc[0][0], 0, 0, 0); \
    acc[0][1] = __builtin_amdgcn_mfma_f32_16x16x32_bf16(a0, b1, acc[0][1], 0, 0, 0); \
    acc[1][0] = __builtin_amdgcn_mfma_f32_16x16x32_bf16(a1, b0, acc[1][0], 0, 0, 0); \
    acc[1][1] = __builtin_amdgcn_mfma_f32_16x16x32_bf16(a1, b1, acc[1][1], 0, 0, 0); \
  }

  if (half == 0){
    #pragma unroll
    for (int k = 0; k < 14; ++k) KSTEP(k)
  } else {
    #pragma unroll
    for (int k = 14; k < K27; ++k) KSTEP(k)
  }
#undef KSTEP

  // combine partials: half==1 waves publish, half==0 waves consume
  if (half == 1){
    #pragma unroll
    for (int t = 0; t < TILES; ++t)
      #pragma unroll
      for (int h = 0; h < 2; ++h)
        #pragma unroll
        for (int r = 0; r < 4; ++r)
          sacc[t*8 + h*4 + r][vw][l] = acc[t][h][r];
  }
  __syncthreads();

  if (half == 0){
    #pragma unroll
    for (int t = 0; t < TILES; ++t)
      #pragma unroll
      for (int h = 0; h < 2; ++h)
        #pragma unroll
        for (int r = 0; r < 4; ++r)
          acc[t][h][r] += sacc[t*8 + h*4 + r][vw][l];

    float s0[2] = {0.f, 0.f}, s1[2] = {0.f, 0.f};
    #pragma unroll
    for (int t = 0; t < TILES; ++t){
      #pragma unroll
      for (int r = 0; r < 4; ++r){
        int row = base + vb + t*16 + g*4 + r;
        if (row < NVOX){
          #pragma unroll
          for (int h = 0; h < 2; ++h){
            float v = acc[t][h][r];
            float* p = trunk + (size_t)row*32 + h*16 + r16;
            if (RES) v += *p;
            *p = v;
            s0[h] += v; s1[h] += v*v;
          }
        }
      }
    }
    #pragma unroll
    for (int h = 0; h < 2; ++h){
      s0[h] += __shfl_xor(s0[h], 16);
      s0[h] += __shfl_xor(s0[h], 32);
      s1[h] += __shfl_xor(s1[h], 16);
      s1[h] += __shfl_xor(s1[h], 32);
    }
    if (l < 16){
      atomicAdd(&sstat[r16],      s0[0]);
      atomicAdd(&sstat[32 + r16], s1[0]);
      atomicAdd(&sstat[16 + r16], s0[1]);
      atomicAdd(&sstat[48 + r16], s1[1]);
    }
  }
  __syncthreads();
  if (tid < 64) atomicAdd(&stats[(blockIdx.x & 63)*64 + tid], sstat[tid]);
}

// ---- MFMA heads with inline final-BN; no block barriers (per-wave LDS only) ----
__global__ void __launch_bounds__(256) heads_mfma_kernel(
    const float* __restrict__ trunk, const float* __restrict__ stats,
    const float* __restrict__ gf, const float* __restrict__ bf,
    const unsigned short* __restrict__ pwh, const float* __restrict__ bcat,
    const float* __restrict__ b_le, const float* __restrict__ w_lr, const float* __restrict__ b_lr,
    float* __restrict__ out){
  __shared__ float lds[4][16][33];
  __shared__ float sbnp[64];
  int tid = threadIdx.x;
  if (tid < 32){
    float s = 0.f, q = 0.f;
    #pragma unroll
    for (int i = 0; i < 64; ++i){ s += stats[i*64 + tid]; q += stats[i*64 + 32 + tid]; }
    float inv = 1.0f / (float)NVOX;
    float mu  = s * inv;
    float var = q * inv - mu*mu;
    float sc  = gf[tid] * rsqrtf(var + 1e-4f);
    sbnp[tid]      = sc;
    sbnp[32 + tid] = bf[tid] - mu*sc;
  }
  __syncthreads();

  int l = tid & 63, w = tid >> 6;
  int g = l >> 4, r16 = l & 15;
  int base = blockIdx.x*256 + w*64;

  bf16x8 B1[6], B2[2];
  #pragma unroll
  for (int f = 0; f < 6; ++f)
    B1[f] = *reinterpret_cast<const bf16x8*>(pwh + f*512 + l*8);
  #pragma unroll
  for (int h = 0; h < 2; ++h)
    B2[h] = *reinterpret_cast<const bf16x8*>(pwh + (6+h)*512 + l*8);

  float sc[8], bi[8];
  #pragma unroll
  for (int i = 0; i < 8; ++i){ sc[i] = sbnp[g*8 + i]; bi[i] = sbnp[32 + g*8 + i]; }
  float wlr0 = w_lr[r16], wlr1 = w_lr[16 + r16];
  float blr  = b_lr[0];
  float bc0  = bcat[r16],      bc1  = bcat[16 + r16];   // b_fe
  float bc2  = bcat[32 + r16], bc3  = bcat[48 + r16];   // b_fr
  float bc4  = bcat[64 + r16], bc5  = bcat[80 + r16];   // b_cls (padded)
  float ble0 = b_le[r16],      ble1 = b_le[16 + r16];

  float* out_e = out + (size_t)NVOX*20;
  float* out_o = out + (size_t)NVOX*52;

  for (int t = 0; t < 4; ++t){
    int arow = base + t*16 + r16;
    f32x4 fa = {0.f,0.f,0.f,0.f}, fb2 = {0.f,0.f,0.f,0.f};
    if (arow < NVOX){
      const f32x4* p = reinterpret_cast<const f32x4*>(trunk + (size_t)arow*32 + g*8);
      fa  = p[0];
      fb2 = p[1];
    }
    ushort8 au;
    au[0] = f2bf(fmaxf(fa.x*sc[0] + bi[0], 0.f));
    au[1] = f2bf(fmaxf(fa.y*sc[1] + bi[1], 0.f));
    au[2] = f2bf(fmaxf(fa.z*sc[2] + bi[2], 0.f));
    au[3] = f2bf(fmaxf(fa.w*sc[3] + bi[3], 0.f));
    au[4] = f2bf(fmaxf(fb2.x*sc[4] + bi[4], 0.f));
    au[5] = f2bf(fmaxf(fb2.y*sc[5] + bi[5], 0.f));
    au[6] = f2bf(fmaxf(fb2.z*sc[6] + bi[6], 0.f));
    au[7] = f2bf(fmaxf(fb2.w*sc[7] + bi[7], 0.f));
    bf16x8 a = __builtin_bit_cast(bf16x8, au);

    f32x4 acc[6];
    #pragma unroll
    for (int j = 0; j < 6; ++j){
      acc[j] = (f32x4){0.f,0.f,0.f,0.f};
      acc[j] = __builtin_amdgcn_mfma_f32_16x16x32_bf16(a, B1[j], acc[j], 0, 0, 0);
    }

    #pragma unroll
    for (int r = 0; r < 4; ++r){
      int orow = base + t*16 + g*4 + r;
      if (orow < NVOX){
        out[(size_t)orow*20 + r16] = acc[4][r] + bc4;           // cls 0..15
        if (r16 < 4)
          out[(size_t)orow*20 + 16 + r16] = acc[5][r] + bc5;    // cls 16..19
      }
    }

    float part[4];
    #pragma unroll
    for (int r = 0; r < 4; ++r)
      part[r] = (acc[2][r] + bc2)*wlr0 + (acc[3][r] + bc3)*wlr1;
    #pragma unroll
    for (int r = 0; r < 4; ++r){
      part[r] += __shfl_xor(part[r], 1);
      part[r] += __shfl_xor(part[r], 2);
      part[r] += __shfl_xor(part[r], 4);
      part[r] += __shfl_xor(part[r], 8);
    }
    if (r16 == 0){
      #pragma unroll
      for (int r = 0; r < 4; ++r){
        int orow = base + t*16 + g*4 + r;
        if (orow < NVOX)
          out_o[orow] = 1.f/(1.f + __expf(-(part[r] + blr)));
      }
    }

    // per-wave LDS repack (wave-internal: no block barrier needed)
    #pragma unroll
    for (int r = 0; r < 4; ++r){
      lds[w][g*4 + r][r16]      = acc[0][r] + bc0;
      lds[w][g*4 + r][16 + r16] = acc[1][r] + bc1;
    }
    ushort8 a2u;
    #pragma unroll
    for (int i = 0; i < 8; ++i)
      a2u[i] = f2bf(lds[w][r16][g*8 + i]);
    bf16x8 a2 = __builtin_bit_cast(bf16x8, a2u);
    f32x4 e0 = (f32x4){0.f,0.f,0.f,0.f}, e1 = (f32x4){0.f,0.f,0.f,0.f};
    e0 = __builtin_amdgcn_mfma_f32_16x16x32_bf16(a2, B2[0], e0, 0, 0, 0);
    e1 = __builtin_amdgcn_mfma_f32_16x16x32_bf16(a2, B2[1], e1, 0, 0, 0);
    #pragma unroll
    for (int r = 0; r < 4; ++r){
      int orow = base + t*16 + g*4 + r;
      if (orow < NVOX){
        out_e[(size_t)orow*32 + r16]      = e0[r] + ble0;
        out_e[(size_t)orow*32 + 16 + r16] = e1[r] + ble1;
      }
    }
  }
}

extern "C" void kernel_launch(void* const* d_in, const int* in_sizes, int n_in,
                              void* d_out, int out_size, void* d_ws, size_t ws_size,
                              hipStream_t stream){
  const float* features = (const float*)d_in[0];
  const int*   nbr      = (const int*)  d_in[1];
  const float* w0       = (const float*)d_in[2];
  const float* bw       = (const float*)d_in[3];
  const float* bg       = (const float*)d_in[4];
  const float* bb       = (const float*)d_in[5];
  const float* gf       = (const float*)d_in[6];
  const float* bf       = (const float*)d_in[7];
  const float* w_cls    = (const float*)d_in[8];
  const float* b_cls    = (const float*)d_in[9];
  const float* w_fe     = (const float*)d_in[10];
  const float* b_fe     = (const float*)d_in[11];
  const float* w_le     = (const float*)d_in[12];
  const float* b_le     = (const float*)d_in[13];
  const float* w_fr     = (const float*)d_in[14];
  const float* b_fr     = (const float*)d_in[15];
  const float* w_lr     = (const float*)d_in[16];
  const float* b_lr     = (const float*)d_in[17];
  float* out = (float*)d_out;

  char* ws = (char*)d_ws;
  float*          trunkA = (float*)(ws);                       // [N][32] f32
  float*          trunkH = (float*)(ws + 38400000);            // [N][32] f32
  f32x4*          fpad   = (f32x4*)(ws + 38400000);            // [N+1][4] f32 (dead before conv1 writes trunkH)
  unsigned short* actB   = (unsigned short*)(ws + 76800000);   // [(N+1)][32] bf16
  unsigned short* pw     = (unsigned short*)(ws + 96000128);   // packed conv weights (221184 B)
  unsigned short* pw0    = (unsigned short*)(ws + 96221312);   // packed conv0 weights (8192 B)
  float*          stats  = (float*)(ws + 96229504);            // 5 x 64 slots x 64 (81920 B)
  unsigned short* pwh    = (unsigned short*)(ws + 96311424);   // packed head weights (8192 B)
  float*          bcat   = (float*)(ws + 96319616);            // 96 f32 head biases

  hipMemsetAsync(stats, 0, 5*64*64*sizeof(float), stream);
  pack_w_kernel<<<(4*K27*2*64 + 4*2*64 + 255)/256, 256, 0, stream>>>(bw, w0, pw, pw0);
  pack_hw_kernel<<<1, 512, 0, stream>>>(w_cls, b_cls, w_fe, b_fe, w_le, w_fr, b_fr, pwh, bcat);
  prepad_kernel<<<(NVOX + 256)/256, 256, 0, stream>>>(features, fpad);

  const int NB  = (NVOX + 255)/256;
  const int NA  = ((NVOX+1)*4 + 255)/256;

  conv0_mfma_kernel<<<NB, 256, 0, stream>>>(fpad, nbr, pw0, trunkA, stats + 0*4096);
  act_kernel<<<NA, 256, 0, stream>>>(trunkA, stats + 0*4096, bg +  0, bb +  0, actB);
  conv_mfma_kernel<false><<<NBLK, 512, 0, stream>>>(actB, nbr, pw + 0*27648, trunkH, stats + 1*4096);
  act_kernel<<<NA, 256, 0, stream>>>(trunkH, stats + 1*4096, bg + 32, bb + 32, actB);
  conv_mfma_kernel<true ><<<NBLK, 512, 0, stream>>>(actB, nbr, pw + 1*27648, trunkA, stats + 2*4096);
  act_kernel<<<NA, 256, 0, stream>>>(trunkA, stats + 2*4096, bg + 64, bb + 64, actB);
  conv_mfma_kernel<false><<<NBLK, 512, 0, stream>>>(actB, nbr, pw + 2*27648, trunkH, stats + 3*4096);
  act_kernel<<<NA, 256, 0, stream>>>(trunkH, stats + 3*4096, bg + 96, bb + 96, actB);
  conv_mfma_kernel<true ><<<NBLK, 512, 0, stream>>>(actB, nbr, pw + 3*27648, trunkA, stats + 4*4096);
  heads_mfma_kernel<<<NB, 256, 0, stream>>>(trunkA, stats + 4*4096, gf, bf, pwh, bcat,
                                            b_le, w_lr, b_lr, out);
}